// Round 8
// baseline (419.158 us; speedup 1.0000x reference)
//
#include <hip/hip_runtime.h>
#include <hip/hip_bf16.h>

#define D_MODEL 1024
#define NHEAD 16
#define HEAD_DIM 64
#define SEQ 1024
#define BATCH 4

typedef unsigned short us;
typedef __attribute__((ext_vector_type(8))) short short8;
typedef __attribute__((ext_vector_type(8))) _Float16 half8;
typedef __attribute__((ext_vector_type(4))) float f32x4;

#define MFMAB __builtin_amdgcn_mfma_f32_16x16x32_bf16
#define MFMAH __builtin_amdgcn_mfma_f32_16x16x32_f16

__device__ __forceinline__ float sigmoidf_(float x) {
  return 1.0f / (1.0f + __expf(-x));
}
__device__ __forceinline__ us f2bf(float x) {
  union { float f; unsigned u; } v; v.f = x;
  unsigned r = v.u + 0x7fffu + ((v.u >> 16) & 1u);
  return (us)(r >> 16);
}
__device__ __forceinline__ float bf2f(us s) {
  union { unsigned u; float f; } v; v.u = ((unsigned)s) << 16; return v.f;
}
__device__ __forceinline__ us f2h(float x) {
  union { _Float16 h; us u; } v; v.h = (_Float16)x; return v.u;
}
__device__ __forceinline__ void async16(us* lds, const us* g) {
  __builtin_amdgcn_global_load_lds(
      (const __attribute__((address_space(1))) unsigned int*)(const void*)g,
      (__attribute__((address_space(3))) unsigned int*)(void*)lds, 16, 0, 0);
}

// ---------------- prep: convert / transpose ---------------------------------
// [0,2048): x -> xh (fp16).  [2048,6144): W^T fp16 (wqkv 3 planes + wo).
// [6144,6208): pe^T (bf16, attn operand).
__global__ __launch_bounds__(256) void prep_k(
    const float* __restrict__ x, const float* __restrict__ Wq,
    const float* __restrict__ Wk, const float* __restrict__ Wv,
    const float* __restrict__ Wo, const float* __restrict__ pe,
    us* __restrict__ xh, us* __restrict__ wqkv, us* __restrict__ wo,
    us* __restrict__ pet)
{
  __shared__ float tile[32][33];
  const int bid = blockIdx.x, tid = threadIdx.x;
  if (bid < 2048) {
    int i0 = bid * 2048 + tid * 8;
    float4 v0 = *(const float4*)(x + i0);
    float4 v1 = *(const float4*)(x + i0 + 4);
    float vv[8] = {v0.x, v0.y, v0.z, v0.w, v1.x, v1.y, v1.z, v1.w};
    short8 hh;
    #pragma unroll
    for (int j = 0; j < 8; ++j) hh[j] = (short)f2h(vv[j]);
    *(short8*)(xh + i0) = hh;
  } else if (bid < 6144) {
    int wj = bid - 2048;
    int w = wj >> 10, t = wj & 1023;
    int k0 = (t >> 5) * 32, n0 = (t & 31) * 32;
    const float* W = (w == 0) ? Wq : (w == 1) ? Wk : (w == 2) ? Wv : Wo;
    us* dst = (w < 3) ? (wqkv + (size_t)w * 1048576) : wo;
    int tx = tid & 31, ty = tid >> 5;
    #pragma unroll
    for (int rep = 0; rep < 4; ++rep) {
      int ky = ty * 4 + rep;
      tile[ky][tx] = W[(size_t)(k0 + ky) * 1024 + n0 + tx];
    }
    __syncthreads();
    #pragma unroll
    for (int rep = 0; rep < 4; ++rep) {
      int ny = ty * 4 + rep;
      int n = n0 + ny, k = k0 + tx;
      dst[(size_t)n * 1024 + k] = f2h(tile[tx][ny]);
    }
  } else {
    int pj = bid - 6144;
    int k0 = (pj & 1) * 32, n0 = (pj >> 1) * 32;
    int tx = tid & 31, ty = tid >> 5;
    #pragma unroll
    for (int rep = 0; rep < 4; ++rep) {
      int ky = ty * 4 + rep;
      tile[ky][tx] = (n0 + tx < 1000) ? pe[(size_t)(k0 + ky) * 1000 + n0 + tx] : 0.f;
    }
    __syncthreads();
    #pragma unroll
    for (int rep = 0; rep < 4; ++rep) {
      int ny = ty * 4 + rep;
      int n = n0 + ny;
      if (n < 1000) pet[(size_t)n * 64 + k0 + tx] = f2bf(tile[tx][ny]);
    }
  }
}

// ---------------- fp16 MFMA GEMM, m97-style, templated tile ------------------
// C[4096, N] = A[4096,1024] @ Bt[N,1024]^T, fp16 in, fp32 accumulate.
// mode 0: seg 0 -> qb (bf16 hbsd), seg 1 -> kb, seg 2 -> vth (bf16 V^T)
// mode 2: fp32 row-major to out0
template<int TM, int TN, int MI, int NJ>
__global__ __launch_bounds__(256) void mgemm(
    const us* __restrict__ A0, const us* __restrict__ B0,
    const float* __restrict__ bias0, const float* __restrict__ bias1,
    const float* __restrict__ bias2,
    void* out0, void* out1, void* out2, int mode)
{
  __shared__ us As[TM][32];
  __shared__ us Bs[TN][32];
  const int tid = threadIdx.x, ln = tid & 63, wv = tid >> 6;
  const int col = ln & 15, quad = ln >> 4;
  const int wr = wv >> 1, wc = wv & 1;
  const int m0 = blockIdx.y * TM, n0 = blockIdx.x * TN;

  f32x4 acc[MI][NJ];
  #pragma unroll
  for (int i = 0; i < MI; ++i)
    #pragma unroll
    for (int j = 0; j < NJ; ++j) acc[i][j] = (f32x4){0.f, 0.f, 0.f, 0.f};

  for (int kt = 0; kt < 1024; kt += 32) {
    #pragma unroll
    for (int j = 0; j < TM / 64; ++j) {
      int c = j * 256 + tid;
      int m = c >> 2;
      int kq = (c & 3) ^ ((c >> 3) & 3);
      async16((us*)&As[0][0] + (size_t)c * 8,
              A0 + (size_t)(m0 + m) * 1024 + kt + kq * 8);
    }
    #pragma unroll
    for (int j = 0; j < TN / 64; ++j) {
      int c = j * 256 + tid;
      int n = c >> 2;
      int kq = (c & 3) ^ ((c >> 3) & 3);
      async16((us*)&Bs[0][0] + (size_t)c * 8,
              B0 + (size_t)(n0 + n) * 1024 + kt + kq * 8);
    }
    __syncthreads();

    half8 a0[MI], b0[NJ];
    #pragma unroll
    for (int i = 0; i < MI; ++i) {
      int r = wr * (TM / 2) + i * 16 + col;
      int q = quad ^ ((r >> 1) & 3);
      a0[i] = *(const half8*)&As[r][q * 8];
    }
    #pragma unroll
    for (int j = 0; j < NJ; ++j) {
      int r = wc * (TN / 2) + j * 16 + col;
      int q = quad ^ ((r >> 1) & 3);
      b0[j] = *(const half8*)&Bs[r][q * 8];
    }
    #pragma unroll
    for (int i = 0; i < MI; ++i)
      #pragma unroll
      for (int j = 0; j < NJ; ++j)
        acc[i][j] = MFMAH(a0[i], b0[j], acc[i][j], 0, 0, 0);
    __syncthreads();
  }

  #pragma unroll
  for (int i = 0; i < MI; ++i)
    #pragma unroll
    for (int j = 0; j < NJ; ++j)
      #pragma unroll
      for (int r = 0; r < 4; ++r) {
        int grow = m0 + wr * (TM / 2) + i * 16 + quad * 4 + r;
        int gcol = n0 + wc * (TN / 2) + j * 16 + col;
        float val = acc[i][j][r];
        if (mode == 0) {
          int seg = gcol >> 10;            // 0=q, 1=k, 2=v (uniform per j)
          int c = gcol & 1023;
          const float* bs = (seg == 0) ? bias0 : (seg == 1) ? bias1 : bias2;
          val += bs[c];
          int h = c >> 6, d = c & 63, b = grow & 3, s = grow >> 2;
          if (seg == 0)
            ((us*)out0)[(size_t)((h * 4 + b) * 1024 + s) * 64 + d] = f2bf(val);
          else if (seg == 1)
            ((us*)out1)[(size_t)((h * 4 + b) * 1024 + s) * 64 + d] = f2bf(val);
          else
            ((us*)out2)[(size_t)((h * 4 + b) * 64 + d) * 1024 + s] = f2bf(val);
        } else {
          val += bias0[gcol];
          ((float*)out0)[(size_t)grow * 1024 + gcol] = val;
        }
      }
}

// ---------------- MFMA fused CoPE attention (r7 kernel, max-free softmax) ---
__global__ __launch_bounds__(1024) void attn_k(
    const us* __restrict__ qb, const us* __restrict__ kb,
    const us* __restrict__ vth, const us* __restrict__ pet,
    us* __restrict__ ah)
{
  __shared__ us S_s[16][1032];
  __shared__ alignas(16) us li_s[16][1024];   // reused as f32x4 reduce buf
  __shared__ float qinv_s[16];

  const int tid = threadIdx.x;
  const int lane = tid & 63;
  const int wv = tid >> 6;
  const int col = lane & 15;
  const int quad = lane >> 4;
  const int id = blockIdx.x;
  const int hb = ((id >> 3) & 7) * 8 + (id & 7);   // id%8 == hb%8 -> same XCD
  const int s0 = (id >> 6) * 16;

  const us* Q = qb + ((size_t)hb * SEQ + s0) * HEAD_DIM;
  const us* K = kb + (size_t)hb * SEQ * HEAD_DIM;
  const us* Vh = vth + (size_t)hb * HEAD_DIM * SEQ;

  short8 aq0 = *(const short8*)(Q + col * 64 + quad * 8);
  short8 aq1 = *(const short8*)(Q + col * 64 + 32 + quad * 8);

  // ---- Phase A: scores for keys [64*wv, 64*wv+64)
  #pragma unroll
  for (int kt = 0; kt < 4; ++kt) {
    int t0 = wv * 64 + kt * 16;
    const us* Kr = K + (size_t)(t0 + col) * 64;
    short8 b0 = *(const short8*)(Kr + quad * 8);
    short8 b1 = *(const short8*)(Kr + 32 + quad * 8);
    f32x4 sc = {0.f, 0.f, 0.f, 0.f};
    sc = MFMAB(aq0, b0, sc, 0, 0, 0);
    sc = MFMAB(aq1, b1, sc, 0, 0, 0);
    #pragma unroll
    for (int r = 0; r < 4; ++r)
      S_s[quad * 4 + r][t0 + col] = f2bf(sc[r] * 0.125f);
  }

  // ---- Phase B: interp logits for positions [64*wv, 64*wv+64)
  #pragma unroll
  for (int nt = 0; nt < 4; ++nt) {
    int n = wv * 64 + nt * 16 + col;
    int nn = (n < 1000) ? n : 999;
    short8 b0 = *(const short8*)(pet + (size_t)nn * 64 + quad * 8);
    short8 b1 = *(const short8*)(pet + (size_t)nn * 64 + 32 + quad * 8);
    f32x4 li = {0.f, 0.f, 0.f, 0.f};
    li = MFMAB(aq0, b0, li, 0, 0, 0);
    li = MFMAB(aq1, b1, li, 0, 0, 0);
    #pragma unroll
    for (int r = 0; r < 4; ++r)
      li_s[quad * 4 + r][n] = f2bf(li[r]);
  }
  __syncthreads();

  // ---- Phase C: query wv — reverse cumsum + CoPE + max-free softmax
  {
    const int q = wv;
    short8 s8a = *(const short8*)&S_s[q][lane * 16];
    short8 s8b = *(const short8*)&S_s[q][lane * 16 + 8];
    float s[16], suf[16];
    #pragma unroll
    for (int j = 0; j < 8; ++j) s[j] = bf2f((us)s8a[j]);
    #pragma unroll
    for (int j = 0; j < 8; ++j) s[8 + j] = bf2f((us)s8b[j]);
    float run = 0.f;
    #pragma unroll
    for (int j = 15; j >= 0; --j) {
      run += sigmoidf_(s[j]);
      suf[j] = run;
    }
    float v = run;
    #pragma unroll
    for (int off = 1; off < 64; off <<= 1) {
      float u = __shfl_down(v, off);
      v += (lane + off < 64) ? u : 0.f;
    }
    float after = v - run;
    // logits bounded (|lg| < ~10): softmax without max subtraction is safe.
    float rs = 0.f;
    short8 p8a, p8b;
    #pragma unroll
    for (int j = 0; j < 16; ++j) {
      float p = fminf(after + suf[j], 999.0f);
      float fl = floorf(p);
      int fi = (int)fl;
      float w = p - fl;
      float lf = bf2f(li_s[q][fi]);
      float lc = bf2f(li_s[q][fi + 1]);   // slots [1000..1023] hold li[999]
      float e = __expf(s[j] + fmaf(lc - lf, w, lf));
      rs += e;
      if (j < 8) p8a[j] = (short)f2bf(e);
      else       p8b[j - 8] = (short)f2bf(e);
    }
    #pragma unroll
    for (int off = 1; off < 64; off <<= 1) rs += __shfl_xor(rs, off);
    *(short8*)&S_s[q][lane * 16] = p8a;
    *(short8*)&S_s[q][lane * 16 + 8] = p8b;
    if (lane == 0) qinv_s[q] = 1.0f / rs;
  }
  __syncthreads();

  // ---- Phase D: O partial = P[:, 256*wk..+256] @ V[256*wk..+256, 16*wd..+16]
  const int wk = wv >> 2, wd = wv & 3;
  const int d0 = wd * 16;
  f32x4 o = {0.f, 0.f, 0.f, 0.f};
  #pragma unroll
  for (int kt = 0; kt < 8; ++kt) {
    int t0 = wk * 256 + kt * 32;
    short8 a = *(const short8*)&S_s[col][t0 + quad * 8];
    short8 bh = *(const short8*)(Vh + (size_t)(d0 + col) * 1024 + t0 + quad * 8);
    o = MFMAB(a, bh, o, 0, 0, 0);
  }
  __syncthreads();                    // li_s reads done; safe to overlay
  f32x4* red = (f32x4*)&li_s[0][0];
  red[wv * 64 + lane] = o;
  __syncthreads();
  if (wv < 4) {
    f32x4 t0v = red[(0 * 4 + wv) * 64 + lane];
    f32x4 t1v = red[(1 * 4 + wv) * 64 + lane];
    f32x4 t2v = red[(2 * 4 + wv) * 64 + lane];
    f32x4 t3v = red[(3 * 4 + wv) * 64 + lane];
    const int b_ = hb & 3, h = hb >> 2;
    #pragma unroll
    for (int r = 0; r < 4; ++r) {
      int q = quad * 4 + r;
      float val = (t0v[r] + t1v[r] + t2v[r] + t3v[r]) * qinv_s[q];
      size_t idx = (size_t)((s0 + q) * 4 + b_) * 1024 + h * 64 + wv * 16 + col;
      ah[idx] = f2h(val);
    }
  }
}

extern "C" void kernel_launch(void* const* d_in, const int* in_sizes, int n_in,
                              void* d_out, int out_size, void* d_ws, size_t ws_size,
                              hipStream_t stream) {
  const float* x  = (const float*)d_in[0];
  const float* Wq = (const float*)d_in[1];
  const float* bq = (const float*)d_in[2];
  const float* Wk = (const float*)d_in[3];
  const float* bk = (const float*)d_in[4];
  const float* Wv = (const float*)d_in[5];
  const float* bv = (const float*)d_in[6];
  const float* Wo = (const float*)d_in[7];
  const float* bo = (const float*)d_in[8];
  const float* pe = (const float*)d_in[9];

  us* w = (us*)d_ws;
  us* xh   = w;                       // 4096x1024 fp16
  us* wqkv = w + 4194304;             // 3072x1024 fp16 (Wq^T|Wk^T|Wv^T)
  us* wo_  = w + 7340032;             // 1024x1024 fp16
  us* pet  = w + 8388608;             // 1000x64 bf16 (+pad)
  us* qb   = w + 8454144;             // 64x1024x64 bf16
  us* kb   = w + 12648448;            // bf16
  us* vth  = w + 16842752;            // 64x64x1024 bf16 (V^T)
  us* ah   = w + 21037056;            // 4096x1024 fp16

  prep_k<<<6208, 256, 0, stream>>>(x, Wq, Wk, Wv, Wo, pe, xh, wqkv, wo_, pet);
  mgemm<128, 128, 4, 4><<<dim3(24, 32), 256, 0, stream>>>(
      xh, wqkv, bq, bk, bv, qb, kb, vth, 0);
  attn_k<<<dim3(4096), 1024, 0, stream>>>(qb, kb, vth, pet, ah);
  mgemm<64, 64, 2, 2><<<dim3(16, 64), 256, 0, stream>>>(
      ah, wo_, bo, nullptr, nullptr, (void*)d_out, nullptr, nullptr, 2);
}

// Round 9
// 386.664 us; speedup vs baseline: 1.0840x; 1.0840x over previous
//
#include <hip/hip_runtime.h>
#include <hip/hip_bf16.h>

#define D_MODEL 1024
#define NHEAD 16
#define HEAD_DIM 64
#define SEQ 1024
#define BATCH 4

typedef unsigned short us;
typedef __attribute__((ext_vector_type(8))) short short8;
typedef __attribute__((ext_vector_type(8))) _Float16 half8;
typedef __attribute__((ext_vector_type(4))) float f32x4;

#define MFMAB __builtin_amdgcn_mfma_f32_16x16x32_bf16
#define MFMAH __builtin_amdgcn_mfma_f32_16x16x32_f16

__device__ __forceinline__ float sigmoidf_(float x) {
  return 1.0f / (1.0f + __expf(-x));
}
__device__ __forceinline__ us f2bf(float x) {
  union { float f; unsigned u; } v; v.f = x;
  unsigned r = v.u + 0x7fffu + ((v.u >> 16) & 1u);
  return (us)(r >> 16);
}
__device__ __forceinline__ float bf2f(us s) {
  union { unsigned u; float f; } v; v.u = ((unsigned)s) << 16; return v.f;
}
__device__ __forceinline__ us f2h(float x) {
  union { _Float16 h; us u; } v; v.h = (_Float16)x; return v.u;
}
__device__ __forceinline__ void async16(us* lds, const us* g) {
  __builtin_amdgcn_global_load_lds(
      (const __attribute__((address_space(1))) unsigned int*)(const void*)g,
      (__attribute__((address_space(3))) unsigned int*)(void*)lds, 16, 0, 0);
}

// ---------------- prep: convert / transpose ---------------------------------
// [0,2048): x -> xh (fp16).  [2048,6144): W^T fp16 (wqkv 3 planes + wo).
// [6144,6208): pe^T (bf16, attn operand).
__global__ __launch_bounds__(256) void prep_k(
    const float* __restrict__ x, const float* __restrict__ Wq,
    const float* __restrict__ Wk, const float* __restrict__ Wv,
    const float* __restrict__ Wo, const float* __restrict__ pe,
    us* __restrict__ xh, us* __restrict__ wqkv, us* __restrict__ wo,
    us* __restrict__ pet)
{
  __shared__ float tile[32][33];
  const int bid = blockIdx.x, tid = threadIdx.x;
  if (bid < 2048) {
    int i0 = bid * 2048 + tid * 8;
    float4 v0 = *(const float4*)(x + i0);
    float4 v1 = *(const float4*)(x + i0 + 4);
    float vv[8] = {v0.x, v0.y, v0.z, v0.w, v1.x, v1.y, v1.z, v1.w};
    short8 hh;
    #pragma unroll
    for (int j = 0; j < 8; ++j) hh[j] = (short)f2h(vv[j]);
    *(short8*)(xh + i0) = hh;
  } else if (bid < 6144) {
    int wj = bid - 2048;
    int w = wj >> 10, t = wj & 1023;
    int k0 = (t >> 5) * 32, n0 = (t & 31) * 32;
    const float* W = (w == 0) ? Wq : (w == 1) ? Wk : (w == 2) ? Wv : Wo;
    us* dst = (w < 3) ? (wqkv + (size_t)w * 1048576) : wo;
    int tx = tid & 31, ty = tid >> 5;
    #pragma unroll
    for (int rep = 0; rep < 4; ++rep) {
      int ky = ty * 4 + rep;
      tile[ky][tx] = W[(size_t)(k0 + ky) * 1024 + n0 + tx];
    }
    __syncthreads();
    #pragma unroll
    for (int rep = 0; rep < 4; ++rep) {
      int ny = ty * 4 + rep;
      int n = n0 + ny, k = k0 + tx;
      dst[(size_t)n * 1024 + k] = f2h(tile[tx][ny]);
    }
  } else {
    int pj = bid - 6144;
    int k0 = (pj & 1) * 32, n0 = (pj >> 1) * 32;
    int tx = tid & 31, ty = tid >> 5;
    #pragma unroll
    for (int rep = 0; rep < 4; ++rep) {
      int ky = ty * 4 + rep;
      tile[ky][tx] = (n0 + tx < 1000) ? pe[(size_t)(k0 + ky) * 1000 + n0 + tx] : 0.f;
    }
    __syncthreads();
    #pragma unroll
    for (int rep = 0; rep < 4; ++rep) {
      int ny = ty * 4 + rep;
      int n = n0 + ny;
      if (n < 1000) pet[(size_t)n * 64 + k0 + tx] = f2bf(tile[tx][ny]);
    }
  }
}

// ---------------- fp16 MFMA GEMM, m97-style, templated tile ------------------
// C[4096, N] = A[4096,1024] @ Bt[N,1024]^T, fp16 in, fp32 accumulate.
// mode 0: seg 0 -> qb (bf16 hbsd), seg 1 -> kb, seg 2 -> vth (bf16 V^T)
// mode 2: fp32 row-major to out0
template<int TM, int TN, int MI, int NJ>
__global__ __launch_bounds__(256) void mgemm(
    const us* __restrict__ A0, const us* __restrict__ B0,
    const float* __restrict__ bias0, const float* __restrict__ bias1,
    const float* __restrict__ bias2,
    void* out0, void* out1, void* out2, int mode)
{
  __shared__ us As[TM][32];
  __shared__ us Bs[TN][32];
  const int tid = threadIdx.x, ln = tid & 63, wv = tid >> 6;
  const int col = ln & 15, quad = ln >> 4;
  const int wr = wv >> 1, wc = wv & 1;
  const int m0 = blockIdx.y * TM, n0 = blockIdx.x * TN;

  f32x4 acc[MI][NJ];
  #pragma unroll
  for (int i = 0; i < MI; ++i)
    #pragma unroll
    for (int j = 0; j < NJ; ++j) acc[i][j] = (f32x4){0.f, 0.f, 0.f, 0.f};

  for (int kt = 0; kt < 1024; kt += 32) {
    #pragma unroll
    for (int j = 0; j < TM / 64; ++j) {
      int c = j * 256 + tid;
      int m = c >> 2;
      int kq = (c & 3) ^ ((c >> 3) & 3);
      async16((us*)&As[0][0] + (size_t)c * 8,
              A0 + (size_t)(m0 + m) * 1024 + kt + kq * 8);
    }
    #pragma unroll
    for (int j = 0; j < TN / 64; ++j) {
      int c = j * 256 + tid;
      int n = c >> 2;
      int kq = (c & 3) ^ ((c >> 3) & 3);
      async16((us*)&Bs[0][0] + (size_t)c * 8,
              B0 + (size_t)(n0 + n) * 1024 + kt + kq * 8);
    }
    __syncthreads();

    half8 a0[MI], b0[NJ];
    #pragma unroll
    for (int i = 0; i < MI; ++i) {
      int r = wr * (TM / 2) + i * 16 + col;
      int q = quad ^ ((r >> 1) & 3);
      a0[i] = *(const half8*)&As[r][q * 8];
    }
    #pragma unroll
    for (int j = 0; j < NJ; ++j) {
      int r = wc * (TN / 2) + j * 16 + col;
      int q = quad ^ ((r >> 1) & 3);
      b0[j] = *(const half8*)&Bs[r][q * 8];
    }
    #pragma unroll
    for (int i = 0; i < MI; ++i)
      #pragma unroll
      for (int j = 0; j < NJ; ++j)
        acc[i][j] = MFMAH(a0[i], b0[j], acc[i][j], 0, 0, 0);
    __syncthreads();
  }

  #pragma unroll
  for (int i = 0; i < MI; ++i)
    #pragma unroll
    for (int j = 0; j < NJ; ++j)
      #pragma unroll
      for (int r = 0; r < 4; ++r) {
        int grow = m0 + wr * (TM / 2) + i * 16 + quad * 4 + r;
        int gcol = n0 + wc * (TN / 2) + j * 16 + col;
        float val = acc[i][j][r];
        if (mode == 0) {
          int seg = gcol >> 10;            // 0=q, 1=k, 2=v (uniform per j)
          int c = gcol & 1023;
          const float* bs = (seg == 0) ? bias0 : (seg == 1) ? bias1 : bias2;
          val += bs[c];
          int h = c >> 6, d = c & 63, b = grow & 3, s = grow >> 2;
          if (seg == 0)
            ((us*)out0)[(size_t)((h * 4 + b) * 1024 + s) * 64 + d] = f2bf(val);
          else if (seg == 1)
            ((us*)out1)[(size_t)((h * 4 + b) * 1024 + s) * 64 + d] = f2bf(val);
          else
            ((us*)out2)[(size_t)((h * 4 + b) * 64 + d) * 1024 + s] = f2bf(val);
        } else {
          val += bias0[gcol];
          ((float*)out0)[(size_t)grow * 1024 + gcol] = val;
        }
      }
}

// ---------------- MFMA fused CoPE attention (r7-exact kernel) ----------------
// Flat grid 4096 with XCD swizzle: all 64 s-tiles of one hb land on one XCD.
__global__ __launch_bounds__(1024) void attn_k(
    const us* __restrict__ qb, const us* __restrict__ kb,
    const us* __restrict__ vth, const us* __restrict__ pet,
    us* __restrict__ ah)
{
  __shared__ us S_s[16][1032];
  __shared__ alignas(16) us li_s[16][1024];   // reused as f32x4 reduce buf
  __shared__ float qinv_s[16];

  const int tid = threadIdx.x;
  const int lane = tid & 63;
  const int wv = tid >> 6;
  const int col = lane & 15;
  const int quad = lane >> 4;
  const int id = blockIdx.x;
  const int hb = ((id >> 3) & 7) * 8 + (id & 7);   // id%8 == hb%8 -> same XCD
  const int s0 = (id >> 6) * 16;

  const us* Q = qb + ((size_t)hb * SEQ + s0) * HEAD_DIM;
  const us* K = kb + (size_t)hb * SEQ * HEAD_DIM;
  const us* Vh = vth + (size_t)hb * HEAD_DIM * SEQ;

  short8 aq0 = *(const short8*)(Q + col * 64 + quad * 8);
  short8 aq1 = *(const short8*)(Q + col * 64 + 32 + quad * 8);

  // ---- Phase A: scores for keys [64*wv, 64*wv+64)
  #pragma unroll
  for (int kt = 0; kt < 4; ++kt) {
    int t0 = wv * 64 + kt * 16;
    const us* Kr = K + (size_t)(t0 + col) * 64;
    short8 b0 = *(const short8*)(Kr + quad * 8);
    short8 b1 = *(const short8*)(Kr + 32 + quad * 8);
    f32x4 sc = {0.f, 0.f, 0.f, 0.f};
    sc = MFMAB(aq0, b0, sc, 0, 0, 0);
    sc = MFMAB(aq1, b1, sc, 0, 0, 0);
    #pragma unroll
    for (int r = 0; r < 4; ++r)
      S_s[quad * 4 + r][t0 + col] = f2bf(sc[r] * 0.125f);
  }

  // ---- Phase B: interp logits for positions [64*wv, 64*wv+64)
  #pragma unroll
  for (int nt = 0; nt < 4; ++nt) {
    int n = wv * 64 + nt * 16 + col;
    int nn = (n < 1000) ? n : 999;
    short8 b0 = *(const short8*)(pet + (size_t)nn * 64 + quad * 8);
    short8 b1 = *(const short8*)(pet + (size_t)nn * 64 + 32 + quad * 8);
    f32x4 li = {0.f, 0.f, 0.f, 0.f};
    li = MFMAB(aq0, b0, li, 0, 0, 0);
    li = MFMAB(aq1, b1, li, 0, 0, 0);
    #pragma unroll
    for (int r = 0; r < 4; ++r)
      li_s[quad * 4 + r][n] = f2bf(li[r]);
  }
  __syncthreads();

  // ---- Phase C: query wv — reverse cumsum + CoPE + softmax (wave-private)
  {
    const int q = wv;
    short8 s8a = *(const short8*)&S_s[q][lane * 16];
    short8 s8b = *(const short8*)&S_s[q][lane * 16 + 8];
    float s[16], suf[16];
    #pragma unroll
    for (int j = 0; j < 8; ++j) s[j] = bf2f((us)s8a[j]);
    #pragma unroll
    for (int j = 0; j < 8; ++j) s[8 + j] = bf2f((us)s8b[j]);
    float run = 0.f;
    #pragma unroll
    for (int j = 15; j >= 0; --j) {
      run += sigmoidf_(s[j]);
      suf[j] = run;
    }
    float v = run;
    #pragma unroll
    for (int off = 1; off < 64; off <<= 1) {
      float u = __shfl_down(v, off);
      v += (lane + off < 64) ? u : 0.f;
    }
    float after = v - run;
    float lg[16];
    float m = -1e30f;
    #pragma unroll
    for (int j = 0; j < 16; ++j) {
      float p = fminf(after + suf[j], 999.0f);
      float fl = floorf(p);
      int fi = (int)fl;
      int ci = (int)ceilf(p);
      float w = p - fl;
      float lf = bf2f(li_s[q][fi]);
      float lc = bf2f(li_s[q][ci]);
      lg[j] = s[j] + lc * w + lf * (1.f - w);
      m = fmaxf(m, lg[j]);
    }
    #pragma unroll
    for (int off = 1; off < 64; off <<= 1) m = fmaxf(m, __shfl_xor(m, off));
    float rs = 0.f;
    short8 p8a, p8b;
    #pragma unroll
    for (int j = 0; j < 8; ++j) {
      float e = __expf(lg[j] - m);
      rs += e;
      p8a[j] = (short)f2bf(e);
    }
    #pragma unroll
    for (int j = 0; j < 8; ++j) {
      float e = __expf(lg[8 + j] - m);
      rs += e;
      p8b[j] = (short)f2bf(e);
    }
    #pragma unroll
    for (int off = 1; off < 64; off <<= 1) rs += __shfl_xor(rs, off);
    *(short8*)&S_s[q][lane * 16] = p8a;
    *(short8*)&S_s[q][lane * 16 + 8] = p8b;
    if (lane == 0) qinv_s[q] = 1.0f / rs;
  }
  __syncthreads();

  // ---- Phase D: O partial = P[:, 256*wk..+256] @ V[256*wk..+256, 16*wd..+16]
  const int wk = wv >> 2, wd = wv & 3;
  const int d0 = wd * 16;
  f32x4 o = {0.f, 0.f, 0.f, 0.f};
  #pragma unroll
  for (int kt = 0; kt < 8; ++kt) {
    int t0 = wk * 256 + kt * 32;
    short8 a = *(const short8*)&S_s[col][t0 + quad * 8];
    short8 bh = *(const short8*)(Vh + (size_t)(d0 + col) * 1024 + t0 + quad * 8);
    o = MFMAB(a, bh, o, 0, 0, 0);
  }
  __syncthreads();                    // li_s reads done; safe to overlay
  f32x4* red = (f32x4*)&li_s[0][0];
  red[wv * 64 + lane] = o;
  __syncthreads();
  if (wv < 4) {
    f32x4 t0v = red[(0 * 4 + wv) * 64 + lane];
    f32x4 t1v = red[(1 * 4 + wv) * 64 + lane];
    f32x4 t2v = red[(2 * 4 + wv) * 64 + lane];
    f32x4 t3v = red[(3 * 4 + wv) * 64 + lane];
    const int b_ = hb & 3, h = hb >> 2;
    #pragma unroll
    for (int r = 0; r < 4; ++r) {
      int q = quad * 4 + r;
      float val = (t0v[r] + t1v[r] + t2v[r] + t3v[r]) * qinv_s[q];
      size_t idx = (size_t)((s0 + q) * 4 + b_) * 1024 + h * 64 + wv * 16 + col;
      ah[idx] = f2h(val);
    }
  }
}

extern "C" void kernel_launch(void* const* d_in, const int* in_sizes, int n_in,
                              void* d_out, int out_size, void* d_ws, size_t ws_size,
                              hipStream_t stream) {
  const float* x  = (const float*)d_in[0];
  const float* Wq = (const float*)d_in[1];
  const float* bq = (const float*)d_in[2];
  const float* Wk = (const float*)d_in[3];
  const float* bk = (const float*)d_in[4];
  const float* Wv = (const float*)d_in[5];
  const float* bv = (const float*)d_in[6];
  const float* Wo = (const float*)d_in[7];
  const float* bo = (const float*)d_in[8];
  const float* pe = (const float*)d_in[9];

  us* w = (us*)d_ws;
  us* xh   = w;                       // 4096x1024 fp16
  us* wqkv = w + 4194304;             // 3072x1024 fp16 (Wq^T|Wk^T|Wv^T)
  us* wo_  = w + 7340032;             // 1024x1024 fp16
  us* pet  = w + 8388608;             // 1000x64 bf16 (+pad)
  us* qb   = w + 8454144;             // 64x1024x64 bf16
  us* kb   = w + 12648448;            // bf16
  us* vth  = w + 16842752;            // 64x64x1024 bf16 (V^T)
  us* ah   = w + 21037056;            // 4096x1024 fp16

  prep_k<<<6208, 256, 0, stream>>>(x, Wq, Wk, Wv, Wo, pe, xh, wqkv, wo_, pet);
  mgemm<128, 128, 4, 4><<<dim3(24, 32), 256, 0, stream>>>(
      xh, wqkv, bq, bk, bv, qb, kb, vth, 0);
  attn_k<<<dim3(4096), 1024, 0, stream>>>(qb, kb, vth, pet, ah);
  mgemm<64, 64, 2, 2><<<dim3(16, 64), 256, 0, stream>>>(
      ah, wo_, bo, nullptr, nullptr, (void*)d_out, nullptr, nullptr, 2);
}